// Round 1
// baseline (202.640 us; speedup 1.0000x reference)
//
#include <hip/hip_runtime.h>

// Problem constants (from reference): S=16, P=65536, N=256, K=32
#define S_DIM 16
#define P_DIM 65536
#define N_ROWS 256
#define K_IDX 32
#define NP ((size_t)N_ROWS * P_DIM)   // 16,777,216 elements per channel

// ---------------------------------------------------------------------------
// Kernel 1: zero-fill the whole output (3*N*P floats) with float4 stores.
// Pure write-bandwidth bound; grid-stride so any grid size is correct.
// ---------------------------------------------------------------------------
__global__ void fill_zero_kernel(float4* __restrict__ out, int n4) {
    int idx = blockIdx.x * blockDim.x + threadIdx.x;
    int stride = gridDim.x * blockDim.x;
    const float4 z = make_float4(0.f, 0.f, 0.f, 0.f);
    for (int i = idx; i < n4; i += stride) {
        out[i] = z;
    }
}

// ---------------------------------------------------------------------------
// Kernel 2: scatter the nonzero values.
// Thread t of block b handles (n = b*8 + t/32, k = t%32).
// count[n, p] = multiplicity of p within indices[n, :] (LDS row broadcast,
// 32 comparisons). out[c, n, p] = 1 - (1 - v_c)^count, computed by repeated
// multiply (exact for integer exponents; count is almost always 1).
// Duplicate k within a row write the same value to the same address: benign.
// ---------------------------------------------------------------------------
__global__ void scatter_kernel(const float* __restrict__ schema_params, // (S,P,4)
                               const int* __restrict__ schema_ids,      // (N)
                               const int* __restrict__ indices,         // (N,K)
                               float* __restrict__ out) {               // (3,N,P)
    __shared__ int lidx[8][K_IDX];

    const int t = threadIdx.x;          // 0..255
    const int nlocal = t >> 5;          // 0..7
    const int k = t & 31;               // 0..31
    const int n = blockIdx.x * 8 + nlocal;

    // Coalesced: global index = blockIdx.x*256 + t
    const int p = indices[n * K_IDX + k];
    lidx[nlocal][k] = p;
    __syncthreads();

    int cnt = 0;
#pragma unroll
    for (int j = 0; j < K_IDX; ++j) {
        cnt += (lidx[nlocal][j] == p) ? 1 : 0;
    }

    const int s = schema_ids[n];
    // (s*P + p)*4 floats -> 16B aligned float4
    const float4 f = *reinterpret_cast<const float4*>(
        schema_params + ((size_t)s * P_DIM + (size_t)p) * 4);

    // PROJ rows: c0 = f2 + f3, c1 = f1, c2 = f3
    const float v0 = f.z + f.w;
    const float v1 = f.y;
    const float v2 = f.w;

    const float b0 = 1.0f - v0;
    const float b1 = 1.0f - v1;
    const float b2 = 1.0f - v2;

    float r0 = 1.0f, r1 = 1.0f, r2 = 1.0f;
    for (int i = 0; i < cnt; ++i) {  // cnt >= 1 always (p matches itself)
        r0 *= b0;
        r1 *= b1;
        r2 *= b2;
    }

    const size_t off = (size_t)n * P_DIM + (size_t)p;
    out[off]          = 1.0f - r0;
    out[NP + off]     = 1.0f - r1;
    out[2 * NP + off] = 1.0f - r2;
}

extern "C" void kernel_launch(void* const* d_in, const int* in_sizes, int n_in,
                              void* d_out, int out_size, void* d_ws, size_t ws_size,
                              hipStream_t stream) {
    const float* schema_params = (const float*)d_in[0]; // (16, 65536, 4) f32
    const int*   schema_ids    = (const int*)d_in[1];   // (256,) i32
    const int*   indices       = (const int*)d_in[2];   // (256, 32) i32
    float*       out           = (float*)d_out;         // (3, 256, 65536) f32 concat

    // 1) zero-fill: out_size = 3*256*65536 = 50,331,648 floats (multiple of 4)
    const int n4 = out_size / 4;                        // 12,582,912 float4s
    const int fill_blocks = 8192;                       // grid-stride, ~6 f4/thread
    fill_zero_kernel<<<fill_blocks, 256, 0, stream>>>((float4*)out, n4);

    // 2) scatter: 256 rows * 32 idx = 8192 threads = 32 blocks of 256
    scatter_kernel<<<N_ROWS * K_IDX / 256, 256, 0, stream>>>(
        schema_params, schema_ids, indices, out);
}

// Round 2
// 201.552 us; speedup vs baseline: 1.0054x; 1.0054x over previous
//
#include <hip/hip_runtime.h>

// Problem constants (from reference): S=16, P=65536, N=256, K=32
#define S_DIM 16
#define P_DIM 65536
#define N_ROWS 256
#define K_IDX 32
#define NP ((size_t)N_ROWS * P_DIM)   // 16,777,216 elements per channel

// ---------------------------------------------------------------------------
// Scatter the nonzero values (output is zeroed by hipMemsetAsync first).
// Thread t of block b handles (n = b*8 + t/32, k = t%32).
// count[n, p] = multiplicity of p within indices[n, :] (LDS row broadcast,
// 32 comparisons). out[c, n, p] = 1 - (1 - v_c)^count, computed by repeated
// multiply (exact for integer exponents; count is almost always 1).
// Duplicate k within a row write the same value to the same address: benign.
// ---------------------------------------------------------------------------
__global__ void scatter_kernel(const float* __restrict__ schema_params, // (S,P,4)
                               const int* __restrict__ schema_ids,      // (N)
                               const int* __restrict__ indices,         // (N,K)
                               float* __restrict__ out) {               // (3,N,P)
    __shared__ int lidx[8][K_IDX];

    const int t = threadIdx.x;          // 0..255
    const int nlocal = t >> 5;          // 0..7
    const int k = t & 31;               // 0..31
    const int n = blockIdx.x * 8 + nlocal;

    // Coalesced: global index = blockIdx.x*256 + t
    const int p = indices[n * K_IDX + k];
    lidx[nlocal][k] = p;
    __syncthreads();

    int cnt = 0;
#pragma unroll
    for (int j = 0; j < K_IDX; ++j) {
        cnt += (lidx[nlocal][j] == p) ? 1 : 0;
    }

    const int s = schema_ids[n];
    // (s*P + p)*4 floats -> 16B aligned float4
    const float4 f = *reinterpret_cast<const float4*>(
        schema_params + ((size_t)s * P_DIM + (size_t)p) * 4);

    // PROJ rows: c0 = f2 + f3, c1 = f1, c2 = f3
    const float v0 = f.z + f.w;
    const float v1 = f.y;
    const float v2 = f.w;

    const float b0 = 1.0f - v0;
    const float b1 = 1.0f - v1;
    const float b2 = 1.0f - v2;

    float r0 = 1.0f, r1 = 1.0f, r2 = 1.0f;
    for (int i = 0; i < cnt; ++i) {  // cnt >= 1 always (p matches itself)
        r0 *= b0;
        r1 *= b1;
        r2 *= b2;
    }

    const size_t off = (size_t)n * P_DIM + (size_t)p;
    out[off]          = 1.0f - r0;
    out[NP + off]     = 1.0f - r1;
    out[2 * NP + off] = 1.0f - r2;
}

extern "C" void kernel_launch(void* const* d_in, const int* in_sizes, int n_in,
                              void* d_out, int out_size, void* d_ws, size_t ws_size,
                              hipStream_t stream) {
    const float* schema_params = (const float*)d_in[0]; // (16, 65536, 4) f32
    const int*   schema_ids    = (const int*)d_in[1];   // (256,) i32
    const int*   indices       = (const int*)d_in[2];   // (256, 32) i32
    float*       out           = (float*)d_out;         // (3, 256, 65536) f32 concat

    // 1) zero-fill via the vendor fill path (measured 6.7-6.8 TB/s on this
    //    device as __amd_rocclr_fillBufferAligned; graph-capturable).
    (void)hipMemsetAsync(d_out, 0, (size_t)out_size * sizeof(float), stream);

    // 2) scatter: 256 rows * 32 idx = 8192 threads = 32 blocks of 256
    scatter_kernel<<<N_ROWS * K_IDX / 256, 256, 0, stream>>>(
        schema_params, schema_ids, indices, out);
}